// Round 4
// baseline (1330.021 us; speedup 1.0000x reference)
//
#include <hip/hip_runtime.h>

#define DFEAT 64
#define BSHIFT 7                 // 128 nodes per bucket
#define BNODES 128
#define MAXB 1024                // supports n <= 131072
#define EPB 8192                 // edges per partition block

// ---------- P1: per-block bucket histogram ----------
__global__ __launch_bounds__(256) void k_p1(
    const int* __restrict__ dst, int E, int* __restrict__ hist, int nblk, int nb) {
    __shared__ int h[MAXB];
    for (int i = threadIdx.x; i < nb; i += 256) h[i] = 0;
    __syncthreads();
    int base = blockIdx.x * EPB;
    int lim = E - base; if (lim > EPB) lim = EPB;
    for (int j = threadIdx.x; j < lim; j += 256)
        atomicAdd(&h[dst[base + j] >> BSHIFT], 1);
    __syncthreads();
    for (int i = threadIdx.x; i < nb; i += 256)
        hist[i * nblk + blockIdx.x] = h[i];   // bucket-major rows
}

// ---------- P2a: bucket totals ----------
__global__ void k_p2a(const int* __restrict__ hist, int nblk, int nb, int* __restrict__ btot) {
    int b = blockIdx.x * blockDim.x + threadIdx.x;
    if (b >= nb) return;
    int s = 0;
    for (int k = 0; k < nblk; ++k) s += hist[b * nblk + k];
    btot[b] = s;
}

// ---------- P2b: exclusive scan of bucket totals (nb <= 1024) ----------
__global__ __launch_bounds__(256) void k_p2b(
    const int* __restrict__ btot, int nb, int* __restrict__ bstart) {
    __shared__ int lds[256];
    __shared__ int pre[257];
    int t = threadIdx.x;
    int c0 = t * 4;
    int v[4]; int s = 0;
#pragma unroll
    for (int j = 0; j < 4; ++j) { v[j] = (c0 + j < nb) ? btot[c0 + j] : 0; s += v[j]; }
    lds[t] = s; __syncthreads();
    if (t == 0) { int run = 0; for (int i = 0; i < 256; ++i) { pre[i] = run; run += lds[i]; } pre[256] = run; }
    __syncthreads();
    int run = pre[t];
#pragma unroll
    for (int j = 0; j < 4; ++j) {
        if (c0 + j < nb) bstart[c0 + j] = run;
        run += v[j];
    }
    if (t == 0) bstart[nb] = pre[256];   // = E
}

// ---------- P2c: per-(bucket,block) global offsets, in place ----------
__global__ void k_p2c(int* __restrict__ hist, int nblk, int nb, const int* __restrict__ bstart) {
    int b = blockIdx.x * blockDim.x + threadIdx.x;
    if (b >= nb) return;
    int run = bstart[b];
    for (int k = 0; k < nblk; ++k) { int v = hist[b * nblk + k]; hist[b * nblk + k] = run; run += v; }
}

// ---------- P3: partition scatter, packed records src | dstLocal<<17 ----------
__global__ __launch_bounds__(256) void k_p3(
    const int* __restrict__ src, const int* __restrict__ dst, int E,
    const int* __restrict__ hist, int nblk, int nb, unsigned int* __restrict__ part) {
    __shared__ int cur[MAXB];
    for (int i = threadIdx.x; i < nb; i += 256) cur[i] = hist[i * nblk + blockIdx.x];
    __syncthreads();
    int base = blockIdx.x * EPB;
    int lim = E - base; if (lim > EPB) lim = EPB;
    for (int j = threadIdx.x; j < lim; j += 256) {
        int d = dst[base + j];
        int s = src[base + j];
        int b = d >> BSHIFT;
        int pos = atomicAdd(&cur[b], 1);
        part[pos] = (unsigned int)s | ((unsigned int)(d & (BNODES - 1)) << 17);
    }
}

// ---------- degrees -> dis, one block per bucket ----------
__global__ __launch_bounds__(256) void k_dis(
    const unsigned int* __restrict__ part, const int* __restrict__ bstart,
    float* __restrict__ dis, int n) {
    __shared__ int cnt[BNODES];
    int b = blockIdx.x;
    int node0 = b << BSHIFT;
    int nn = n - node0; if (nn > BNODES) nn = BNODES;
    if (threadIdx.x < BNODES) cnt[threadIdx.x] = 0;
    __syncthreads();
    int beg = bstart[b], end = bstart[b + 1];
    for (int i = beg + threadIdx.x; i < end; i += 256)
        atomicAdd(&cnt[part[i] >> 17], 1);
    __syncthreads();
    if (threadIdx.x < nn)
        dis[node0 + threadIdx.x] = rsqrtf((float)cnt[threadIdx.x] + 1.0f);
}

// ---------- tall-skinny GEMM: g = (X @ W) * dis ----------
__global__ __launch_bounds__(256) void k_gemm_scale(
    const float* __restrict__ X, const float* __restrict__ W,
    const float* __restrict__ dis, float* __restrict__ g, int n) {
    __shared__ float Ws[64 * 64];
    __shared__ float Xs[64 * 64];

    for (int i = threadIdx.x; i < 64 * 64; i += 256) Ws[i] = W[i];

    int row0 = blockIdx.x * 64;
    int rows = n - row0; if (rows > 64) rows = 64;
    for (int i = threadIdx.x; i < rows * 64; i += 256)
        Xs[i] = X[(size_t)row0 * 64 + i];
    __syncthreads();

    int d  = threadIdx.x & 63;
    int rg = threadIdx.x >> 6;

    float acc[16];
#pragma unroll
    for (int r = 0; r < 16; ++r) acc[r] = 0.f;

#pragma unroll 16
    for (int k = 0; k < 64; ++k) {
        float w = Ws[k * 64 + d];
#pragma unroll
        for (int r = 0; r < 16; ++r)
            acc[r] = fmaf(Xs[(rg * 16 + r) * 64 + k], w, acc[r]);
    }

#pragma unroll
    for (int r = 0; r < 16; ++r) {
        int row = rg * 16 + r;
        if (row < rows)
            g[(size_t)(row0 + row) * 64 + d] = acc[r] * dis[row0 + row];
    }
}

// ---------- fused aggregate + epilogue, one bucket per block ----------
// LDS tile acc[128][64]; out = relu(dis[v]*(acc[v]+g[v]) + b) [+ resid]
__global__ __launch_bounds__(256) void k_agg(
    const float* __restrict__ g, const unsigned int* __restrict__ part,
    const int* __restrict__ bstart, const float* __restrict__ dis,
    const float* __restrict__ bias, const float* __restrict__ resid,
    float* __restrict__ out, int n) {
    __shared__ float acc[BNODES * DFEAT];   // 32 KB
    int b = blockIdx.x;
    int node0 = b << BSHIFT;
    int nn = n - node0; if (nn > BNODES) nn = BNODES;

    for (int i = threadIdx.x; i < BNODES * DFEAT; i += 256) acc[i] = 0.f;
    __syncthreads();

    int beg = bstart[b], end = bstart[b + 1];
    int lane = threadIdx.x & 63;
    int wid  = threadIdx.x >> 6;   // 4 waves, each takes every 4th edge

    int i = beg + wid;
    // 4 edges in flight per wave
    for (; i + 12 < end; i += 16) {
        unsigned int p0 = part[i], p1 = part[i + 4], p2 = part[i + 8], p3 = part[i + 12];
        float v0 = g[(size_t)(p0 & 0x1FFFF) * DFEAT + lane];
        float v1 = g[(size_t)(p1 & 0x1FFFF) * DFEAT + lane];
        float v2 = g[(size_t)(p2 & 0x1FFFF) * DFEAT + lane];
        float v3 = g[(size_t)(p3 & 0x1FFFF) * DFEAT + lane];
        atomicAdd(&acc[(p0 >> 17) * DFEAT + lane], v0);
        atomicAdd(&acc[(p1 >> 17) * DFEAT + lane], v1);
        atomicAdd(&acc[(p2 >> 17) * DFEAT + lane], v2);
        atomicAdd(&acc[(p3 >> 17) * DFEAT + lane], v3);
    }
    for (; i < end; i += 4) {
        unsigned int p = part[i];
        float v = g[(size_t)(p & 0x1FFFF) * DFEAT + lane];
        atomicAdd(&acc[(p >> 17) * DFEAT + lane], v);
    }
    __syncthreads();

    for (int t = threadIdx.x; t < nn * DFEAT; t += 256) {
        int node = node0 + (t >> 6);
        int d = t & 63;
        float self = g[(size_t)node * DFEAT + d];
        float v = fmaxf(fmaf(acc[t] + self, dis[node], bias[d]), 0.f);
        if (resid) v += resid[(size_t)node * DFEAT + d];
        out[(size_t)node * DFEAT + d] = v;
    }
}

// ======================= launch =======================

extern "C" void kernel_launch(void* const* d_in, const int* in_sizes, int n_in,
                              void* d_out, int out_size, void* d_ws, size_t ws_size,
                              hipStream_t stream) {
    const float* x  = (const float*)d_in[0];
    const int*   ei = (const int*)  d_in[1];
    const float* W1 = (const float*)d_in[2];
    const float* b1 = (const float*)d_in[3];
    const float* W2 = (const float*)d_in[4];
    const float* b2 = (const float*)d_in[5];
    float* out = (float*)d_out;

    const int n = in_sizes[0] / DFEAT;     // 100000
    const int E = in_sizes[1] / 2;         // 1250000
    const int* src = ei;
    const int* dst = ei + E;

    const int nb   = (n + BNODES - 1) >> BSHIFT;     // buckets (782)
    const int nblk = (E + EPB - 1) / EPB;            // partition blocks (153)

    // workspace carve-up (4B elems)
    int*          hist   = (int*)d_ws;                          // nb*nblk
    int*          btot   = hist + ((nb * nblk + 3) & ~3);       // nb
    int*          bstart = btot + ((nb + 3) & ~3);              // nb+1
    unsigned int* part   = (unsigned int*)(bstart + ((nb + 1 + 3) & ~3));  // E
    float*        dis    = (float*)(part + ((E + 3) & ~3));     // n
    float*        g      = dis + ((n + 3) & ~3);                // n*64
    float*        h      = g + (size_t)n * DFEAT;               // n*64

    const int B256 = 256;
    const int gT   = (n + 63) / 64;
    const int gB   = (nb + B256 - 1) / B256;

    // ---- bucket partition build (replaces full CSR) ----
    k_p1 <<<nblk, B256, 0, stream>>>(dst, E, hist, nblk, nb);
    k_p2a<<<gB,   B256, 0, stream>>>(hist, nblk, nb, btot);
    k_p2b<<<1,    B256, 0, stream>>>(btot, nb, bstart);
    k_p2c<<<gB,   B256, 0, stream>>>(hist, nblk, nb, bstart);
    k_p3 <<<nblk, B256, 0, stream>>>(src, dst, E, hist, nblk, nb, part);
    k_dis<<<nb,   B256, 0, stream>>>(part, bstart, dis, n);

    // ---- layer 1 ----
    k_gemm_scale<<<gT, B256, 0, stream>>>(x, W1, dis, g, n);
    k_agg       <<<nb, B256, 0, stream>>>(g, part, bstart, dis, b1, nullptr, h, n);

    // ---- layer 2 ----
    k_gemm_scale<<<gT, B256, 0, stream>>>(h, W2, dis, g, n);
    k_agg       <<<nb, B256, 0, stream>>>(g, part, bstart, dis, b2, x, out, n);
}

// Round 6
// 307.762 us; speedup vs baseline: 4.3216x; 4.3216x over previous
//
#include <hip/hip_runtime.h>

#define DFEAT 64
#define BSHIFT 7                 // 128 nodes per bucket
#define BNODES 128
#define MAXB 1024                // supports n <= 131072 nodes, nb <= 1024 buckets
#define EPB 2048                 // edges per partition block

typedef unsigned int uint32;
typedef unsigned short ushort16;

// ---------- bf16 helpers ----------
__device__ __forceinline__ ushort16 f2bf(float f) {
    uint32 u = __float_as_uint(f);
    u += 0x7fffu + ((u >> 16) & 1u);   // round-to-nearest-even
    return (ushort16)(u >> 16);
}
__device__ __forceinline__ float bf_lo(uint32 u) { return __uint_as_float(u << 16); }
__device__ __forceinline__ float bf_hi(uint32 u) { return __uint_as_float(u & 0xffff0000u); }

// ---------- P1: per-block bucket histogram ----------
__global__ __launch_bounds__(256) void k_p1(
    const int* __restrict__ dst, int E, int* __restrict__ hist, int nblk, int nb) {
    __shared__ int h[MAXB];
    for (int i = threadIdx.x; i < nb; i += 256) h[i] = 0;
    __syncthreads();
    int base = blockIdx.x * EPB;
    int lim = E - base; if (lim > EPB) lim = EPB;
    for (int j = threadIdx.x; j < lim; j += 256)
        atomicAdd(&h[dst[base + j] >> BSHIFT], 1);
    __syncthreads();
    for (int i = threadIdx.x; i < nb; i += 256)
        hist[(size_t)i * nblk + blockIdx.x] = h[i];   // bucket-major rows
}

// ---------- P2a: bucket totals (one wave per bucket) ----------
__global__ __launch_bounds__(256) void k_p2a(
    const int* __restrict__ hist, int nblk, int nb, int* __restrict__ btot) {
    int w = (blockIdx.x * 256 + threadIdx.x) >> 6;
    int lane = threadIdx.x & 63;
    if (w >= nb) return;
    size_t base = (size_t)w * nblk;
    int s = 0;
    for (int k = lane; k < nblk; k += 64) s += hist[base + k];
#pragma unroll
    for (int d = 1; d < 64; d <<= 1) s += __shfl_xor(s, d, 64);
    if (lane == 0) btot[w] = s;
}

// ---------- P2b: exclusive scan of bucket totals (nb <= 1024) ----------
__global__ __launch_bounds__(256) void k_p2b(
    const int* __restrict__ btot, int nb, int* __restrict__ bstart) {
    __shared__ int lds[256];
    __shared__ int pre[257];
    int t = threadIdx.x;
    int c0 = t * 4;
    int v[4]; int s = 0;
#pragma unroll
    for (int j = 0; j < 4; ++j) { v[j] = (c0 + j < nb) ? btot[c0 + j] : 0; s += v[j]; }
    lds[t] = s; __syncthreads();
    if (t == 0) { int run = 0; for (int i = 0; i < 256; ++i) { pre[i] = run; run += lds[i]; } pre[256] = run; }
    __syncthreads();
    int run = pre[t];
#pragma unroll
    for (int j = 0; j < 4; ++j) {
        if (c0 + j < nb) bstart[c0 + j] = run;
        run += v[j];
    }
    if (t == 0) bstart[nb] = pre[256];   // = E
}

// ---------- P2c: per-(bucket,block) global offsets, wave-parallel scan per bucket ----------
__global__ __launch_bounds__(256) void k_p2c(
    int* __restrict__ hist, int nblk, int nb, const int* __restrict__ bstart) {
    int w = (blockIdx.x * 256 + threadIdx.x) >> 6;
    int lane = threadIdx.x & 63;
    if (w >= nb) return;
    size_t base = (size_t)w * nblk;
    int run = bstart[w];
    for (int c = 0; c < nblk; c += 64) {
        int k = c + lane;
        int v = (k < nblk) ? hist[base + k] : 0;
        int sc = v;
#pragma unroll
        for (int d = 1; d < 64; d <<= 1) { int t = __shfl_up(sc, d, 64); if (lane >= d) sc += t; }
        if (k < nblk) hist[base + k] = run + sc - v;   // exclusive
        run += __shfl(sc, 63, 64);
    }
}

// ---------- P3: partition scatter, packed records src | dstLocal<<17 ----------
__global__ __launch_bounds__(256) void k_p3(
    const int* __restrict__ src, const int* __restrict__ dst, int E,
    const int* __restrict__ hist, int nblk, int nb, uint32* __restrict__ part) {
    __shared__ int cur[MAXB];
    for (int i = threadIdx.x; i < nb; i += 256) cur[i] = hist[(size_t)i * nblk + blockIdx.x];
    __syncthreads();
    int base = blockIdx.x * EPB;
    int lim = E - base; if (lim > EPB) lim = EPB;
    for (int j = threadIdx.x; j < lim; j += 256) {
        int d = dst[base + j];
        int s = src[base + j];
        int b = d >> BSHIFT;
        int pos = atomicAdd(&cur[b], 1);
        part[pos] = (uint32)s | ((uint32)(d & (BNODES - 1)) << 17);
    }
}

// ---------- per-bucket counting sort -> CSR (row_ptr, col) + dis ----------
__global__ __launch_bounds__(256) void k_sort(
    const uint32* __restrict__ part, const int* __restrict__ bstart,
    int* __restrict__ row_ptr, int* __restrict__ col, float* __restrict__ dis,
    int n, int nb) {
    __shared__ int cnt[BNODES];
    __shared__ int off[BNODES + 1];
    int b = blockIdx.x;
    int node0 = b << BSHIFT;
    int nn = n - node0; if (nn > BNODES) nn = BNODES;

    if (threadIdx.x < BNODES) cnt[threadIdx.x] = 0;
    __syncthreads();
    int beg = bstart[b], end = bstart[b + 1];
    for (int i = beg + threadIdx.x; i < end; i += 256)
        atomicAdd(&cnt[part[i] >> 17], 1);
    __syncthreads();
    if (threadIdx.x == 0) {
        int run = beg;
        for (int j = 0; j < BNODES; ++j) { off[j] = run; run += cnt[j]; }
        off[BNODES] = run;
    }
    __syncthreads();
    if (threadIdx.x < nn) {
        row_ptr[node0 + threadIdx.x] = off[threadIdx.x];
        dis[node0 + threadIdx.x] = rsqrtf((float)cnt[threadIdx.x] + 1.0f);  // +1 self-loop
    }
    if (b == nb - 1 && threadIdx.x == 0) row_ptr[n] = end;
    if (threadIdx.x < BNODES) cnt[threadIdx.x] = 0;   // reuse as cursor
    __syncthreads();
    for (int i = beg + threadIdx.x; i < end; i += 256) {
        uint32 p = part[i];
        int j = p >> 17;
        int pos = off[j] + atomicAdd(&cnt[j], 1);
        col[pos] = (int)(p & 0x1FFFFu);    // writes stay inside this bucket's range
    }
}

// ---------- tall-skinny GEMM: g_bf16 = bf16((X @ W) * dis) ----------
__global__ __launch_bounds__(256) void k_gemm_scale(
    const float* __restrict__ X, const float* __restrict__ W,
    const float* __restrict__ dis, ushort16* __restrict__ gb, int n) {
    __shared__ float Ws[64 * 64];
    __shared__ float Xs[64 * 64];

    for (int i = threadIdx.x; i < 64 * 64; i += 256) Ws[i] = W[i];

    int row0 = blockIdx.x * 64;
    int rows = n - row0; if (rows > 64) rows = 64;
    for (int i = threadIdx.x; i < rows * 64; i += 256)
        Xs[i] = X[(size_t)row0 * 64 + i];
    __syncthreads();

    int d  = threadIdx.x & 63;
    int rg = threadIdx.x >> 6;

    float acc[16];
#pragma unroll
    for (int r = 0; r < 16; ++r) acc[r] = 0.f;

#pragma unroll 16
    for (int k = 0; k < 64; ++k) {
        float w = Ws[k * 64 + d];
#pragma unroll
        for (int r = 0; r < 16; ++r)
            acc[r] = fmaf(Xs[(rg * 16 + r) * 64 + k], w, acc[r]);
    }

#pragma unroll
    for (int r = 0; r < 16; ++r) {
        int row = rg * 16 + r;
        if (row < rows)
            gb[(size_t)(row0 + row) * 64 + d] = f2bf(acc[r] * dis[row0 + row]);
    }
}

// ---------- fused aggregate + epilogue (wave per node, bf16 gather) ----------
// lanes 0-31 process even-index edges, lanes 32-63 odd-index; each lane reads one
// dword (2 bf16 feats) of the 128B row; halves combined by shfl_xor(32) at the end.
__global__ __launch_bounds__(256) void k_aggregate(
    const ushort16* __restrict__ gb, const int* __restrict__ row_ptr,
    const int* __restrict__ col, const float* __restrict__ dis,
    const float* __restrict__ bias, const float* __restrict__ resid,
    float* __restrict__ out, int n) {
    int node = blockIdx.x * 4 + (threadIdx.x >> 6);
    if (node >= n) return;
    int lane = threadIdx.x & 63;
    int half = lane >> 5;
    int sub  = lane & 31;
    const uint32* gu = (const uint32*)gb;

    int beg = row_ptr[node], end = row_ptr[node + 1];
    float a0 = 0.f, a1 = 0.f;

    {   // self-loop term, counted once (half 0 only)
        uint32 u = gu[(size_t)node * 32 + sub];
        if (half == 0) { a0 += bf_lo(u); a1 += bf_hi(u); }
    }

    int i = beg;
    for (; i + 8 <= end; i += 8) {      // 8 edges/iter, 4 row-loads in flight per lane
        int c0 = col[i     + half];
        int c1 = col[i + 2 + half];
        int c2 = col[i + 4 + half];
        int c3 = col[i + 6 + half];
        uint32 u0 = gu[(size_t)c0 * 32 + sub];
        uint32 u1 = gu[(size_t)c1 * 32 + sub];
        uint32 u2 = gu[(size_t)c2 * 32 + sub];
        uint32 u3 = gu[(size_t)c3 * 32 + sub];
        a0 += bf_lo(u0); a1 += bf_hi(u0);
        a0 += bf_lo(u1); a1 += bf_hi(u1);
        a0 += bf_lo(u2); a1 += bf_hi(u2);
        a0 += bf_lo(u3); a1 += bf_hi(u3);
    }
    for (; i < end; i += 2) {
        int idx = i + half;
        if (idx < end) {
            uint32 u = gu[(size_t)col[idx] * 32 + sub];
            a0 += bf_lo(u); a1 += bf_hi(u);
        }
    }

    a0 += __shfl_xor(a0, 32, 64);
    a1 += __shfl_xor(a1, 32, 64);

    if (half == 0) {
        float dn = dis[node];
        float v0 = fmaxf(fmaf(a0, dn, bias[2 * sub]),     0.f);
        float v1 = fmaxf(fmaf(a1, dn, bias[2 * sub + 1]), 0.f);
        if (resid) {
            v0 += resid[(size_t)node * DFEAT + 2 * sub];
            v1 += resid[(size_t)node * DFEAT + 2 * sub + 1];
        }
        float2 r = make_float2(v0, v1);
        *reinterpret_cast<float2*>(out + (size_t)node * DFEAT + 2 * sub) = r;
    }
}

// ======================= launch =======================

extern "C" void kernel_launch(void* const* d_in, const int* in_sizes, int n_in,
                              void* d_out, int out_size, void* d_ws, size_t ws_size,
                              hipStream_t stream) {
    const float* x  = (const float*)d_in[0];
    const int*   ei = (const int*)  d_in[1];
    const float* W1 = (const float*)d_in[2];
    const float* b1 = (const float*)d_in[3];
    const float* W2 = (const float*)d_in[4];
    const float* b2 = (const float*)d_in[5];
    float* out = (float*)d_out;

    const int n = in_sizes[0] / DFEAT;     // 100000
    const int E = in_sizes[1] / 2;         // 1250000
    const int* src = ei;
    const int* dst = ei + E;

    const int nb   = (n + BNODES - 1) >> BSHIFT;     // 782 buckets
    const int nblk = (E + EPB - 1) / EPB;            // 611 partition blocks

    // workspace carve-up (4B elems)
    int*      hist    = (int*)d_ws;                                  // nb*nblk
    int*      btot    = hist + (((size_t)nb * nblk + 3) & ~3);       // nb
    int*      bstart  = btot + ((nb + 3) & ~3);                      // nb+1
    uint32*   part    = (uint32*)(bstart + ((nb + 1 + 3) & ~3));     // E
    int*      row_ptr = (int*)(part + ((E + 3) & ~3));               // n+1
    int*      col     = row_ptr + ((n + 1 + 3) & ~3);                // E
    float*    dis     = (float*)(col + ((E + 3) & ~3));              // n
    ushort16* gb      = (ushort16*)(dis + ((n + 3) & ~3));           // n*64 bf16
    float*    h       = (float*)(gb + (((size_t)n * DFEAT + 1) & ~1)); // n*64 f32

    const int B256 = 256;
    const int gT   = (n + 63) / 64;
    const int gW   = ((nb * 64) + B256 - 1) / B256;   // wave-per-bucket kernels
    const int gAg  = (n + 3) / 4;

    // ---- bucket partition + per-bucket sort -> CSR ----
    k_p1  <<<nblk, B256, 0, stream>>>(dst, E, hist, nblk, nb);
    k_p2a <<<gW,   B256, 0, stream>>>(hist, nblk, nb, btot);
    k_p2b <<<1,    B256, 0, stream>>>(btot, nb, bstart);
    k_p2c <<<gW,   B256, 0, stream>>>(hist, nblk, nb, bstart);
    k_p3  <<<nblk, B256, 0, stream>>>(src, dst, E, hist, nblk, nb, part);
    k_sort<<<nb,   B256, 0, stream>>>(part, bstart, row_ptr, col, dis, n, nb);

    // ---- layer 1 ----
    k_gemm_scale<<<gT,  B256, 0, stream>>>(x, W1, dis, gb, n);
    k_aggregate <<<gAg, B256, 0, stream>>>(gb, row_ptr, col, dis, b1, nullptr, h, n);

    // ---- layer 2 ----
    k_gemm_scale<<<gT,  B256, 0, stream>>>(h, W2, dis, gb, n);
    k_aggregate <<<gAg, B256, 0, stream>>>(gb, row_ptr, col, dis, b2, x, out, n);
}